// Round 2
// baseline (320.669 us; speedup 1.0000x reference)
//
#include <hip/hip_runtime.h>

#define PI_F 3.14159265358979323846f

#define FMA4S(acc, a, b)                  \
    acc.x = fmaf(a, b.x, acc.x);          \
    acc.y = fmaf(a, b.y, acc.y);          \
    acc.z = fmaf(a, b.z, acc.z);          \
    acc.w = fmaf(a, b.w, acc.w)

// ---------------------------------------------------------------------------
// Kernel 1 (v2): build the 32x64 combined operator
//   C = B26 @ (M64^3)[:26,:]  where  B26[h,h1] = (M32^3)[h1,h]  (h1 < 26)
// Rewritten via the truncated decomposition
//   C = ((B26 @ M64[:26,:]) @ M64) @ M64
// so no full 64^3 cube is ever formed, and all operand reads are float4
// ds_read_b128 (broadcast across lane groups; <=2-way bank aliasing).
// v1 did ~24.5k scalar LDS wave-instrs on one CU (~60 us est); v2 ~1.7k.
// ---------------------------------------------------------------------------
__global__ __launch_bounds__(1024) void build_C_kernel(float* __restrict__ Cout) {
    __shared__ __align__(16) float sM[64 * 64];    // M64
    __shared__ __align__(16) float s32a[32 * 32];  // M32
    __shared__ __align__(16) float s32b[32 * 32];  // M32^2
    __shared__ __align__(16) float s32c[32 * 32];  // M32^3
    __shared__ __align__(16) float sW[32 * 64];    // B26 @ M64[:26,:]
    __shared__ __align__(16) float sW2[32 * 64];   // sW @ M64
    const int t = threadIdx.x;

    // --- fill M64 (exact integer mod-2pi reduction of cos args) ---
    for (int i = t; i < 4096; i += 1024) {
        int k = i >> 6, n = i & 63;
        int m = ((2 * n + 1) * k) & 255;               // cos(pi*m/128): period 256
        float v = (k == 0) ? 0.125f                     // 1/sqrt(64)
                           : 0.17677669529663688f       // sqrt(2/64)
                             * cosf(PI_F * (float)m / 128.0f);
        sM[i] = v;
    }
    // --- fill M32 ---
    {
        int k = t >> 5, n = t & 31;
        int m = ((2 * n + 1) * k) & 127;               // cos(pi*m/64): period 128
        float v = (k == 0) ? 0.17677669529663688f       // 1/sqrt(32)
                           : 0.25f                      // sqrt(2/32)
                             * cosf(PI_F * (float)m / 64.0f);
        s32a[t] = v;
    }
    __syncthreads();

    // --- s32b = M32 @ M32 (256 float4-threads) ---
    if (t < 256) {
        int r = t >> 3, q = t & 7;
        float4 acc = make_float4(0.f, 0.f, 0.f, 0.f);
#pragma unroll 8
        for (int k = 0; k < 32; ++k) {
            float a = s32a[r * 32 + k];
            float4 b = *(const float4*)&s32a[k * 32 + q * 4];
            FMA4S(acc, a, b);
        }
        *(float4*)&s32b[r * 32 + q * 4] = acc;
    }
    __syncthreads();

    // --- s32c = s32b @ M32 ---
    if (t < 256) {
        int r = t >> 3, q = t & 7;
        float4 acc = make_float4(0.f, 0.f, 0.f, 0.f);
#pragma unroll 8
        for (int k = 0; k < 32; ++k) {
            float a = s32b[r * 32 + k];
            float4 b = *(const float4*)&s32a[k * 32 + q * 4];
            FMA4S(acc, a, b);
        }
        *(float4*)&s32c[r * 32 + q * 4] = acc;
    }
    __syncthreads();

    // --- sW[r][4q..] = sum_{h1<26} s32c[h1*32 + r] * M64[h1][4q..] ---
    if (t < 512) {
        int r = t >> 4, q = t & 15;
        float4 acc = make_float4(0.f, 0.f, 0.f, 0.f);
#pragma unroll 13
        for (int h1 = 0; h1 < 26; ++h1) {
            float a = s32c[h1 * 32 + r];               // consecutive r -> adjacent banks
            float4 b = *(const float4*)&sM[h1 * 64 + q * 4];
            FMA4S(acc, a, b);
        }
        *(float4*)&sW[r * 64 + q * 4] = acc;
    }
    __syncthreads();

    // --- sW2 = sW @ M64 (A operand read as float4 per 4 k's) ---
    if (t < 512) {
        int r = t >> 4, q = t & 15;
        float4 acc = make_float4(0.f, 0.f, 0.f, 0.f);
#pragma unroll 4
        for (int k4 = 0; k4 < 64; k4 += 4) {
            float4 a4 = *(const float4*)&sW[r * 64 + k4];
            float4 b0 = *(const float4*)&sM[(k4 + 0) * 64 + q * 4];
            float4 b1 = *(const float4*)&sM[(k4 + 1) * 64 + q * 4];
            float4 b2 = *(const float4*)&sM[(k4 + 2) * 64 + q * 4];
            float4 b3 = *(const float4*)&sM[(k4 + 3) * 64 + q * 4];
            FMA4S(acc, a4.x, b0);
            FMA4S(acc, a4.y, b1);
            FMA4S(acc, a4.z, b2);
            FMA4S(acc, a4.w, b3);
        }
        *(float4*)&sW2[r * 64 + q * 4] = acc;
    }
    __syncthreads();

    // --- C = sW2 @ M64 -> global (32x64) ---
    if (t < 512) {
        int r = t >> 4, q = t & 15;
        float4 acc = make_float4(0.f, 0.f, 0.f, 0.f);
#pragma unroll 4
        for (int k4 = 0; k4 < 64; k4 += 4) {
            float4 a4 = *(const float4*)&sW2[r * 64 + k4];
            float4 b0 = *(const float4*)&sM[(k4 + 0) * 64 + q * 4];
            float4 b1 = *(const float4*)&sM[(k4 + 1) * 64 + q * 4];
            float4 b2 = *(const float4*)&sM[(k4 + 2) * 64 + q * 4];
            float4 b3 = *(const float4*)&sM[(k4 + 3) * 64 + q * 4];
            FMA4S(acc, a4.x, b0);
            FMA4S(acc, a4.y, b1);
            FMA4S(acc, a4.z, b2);
            FMA4S(acc, a4.w, b3);
        }
        *(float4*)&Cout[r * 64 + q * 4] = acc;
    }
}

// ---------------------------------------------------------------------------
// Kernel 2 (UNCHANGED from the harness-verified 324.4 us version):
//   out[bc,d,h,w] = (d<26 && w<26) ? sum_k C[h,k] * x[bc,d,k,w] : 0
// One wave per (bc,d) slice; block = 4 slices. Lane l: wq=l&7, hb=l>>3,
// h in {hb, hb+8, hb+16, hb+24}. x tile (64x32 fp32 = 8 KB/slice) staged via
// global_load_lds width 16. sC stride 68: rows 16 B-aligned for ds_read_b128;
// 68%32==4 tiles all 32 banks across the 8 hb groups.
// Inner loop per 4 k's: 8 ds_read_b128 + 64 fma.
// ---------------------------------------------------------------------------
#define FMA4(a, c, xv)                    \
    a.x = fmaf(c, xv.x, a.x);             \
    a.y = fmaf(c, xv.y, a.y);             \
    a.z = fmaf(c, xv.z, a.z);             \
    a.w = fmaf(c, xv.w, a.w)

__global__ __launch_bounds__(256) void spectral_pool_kernel(
    const float* __restrict__ x, const float* __restrict__ C,
    float* __restrict__ out) {
    __shared__ __align__(16) float sC[32 * 68];
    __shared__ __align__(16) float xs[4][64 * 32];

    const int t   = threadIdx.x;
    const int blk = blockIdx.x;
    const int bc  = blk >> 3;   // 0..255 (b*32 + c)
    const int dg  = blk & 7;    // d-group of 4
    const int s   = t >> 6;     // wave id = slice
    const int l   = t & 63;
    const int wq  = l & 7;      // w-quad
    const int hb  = l >> 3;     // h base 0..7
    const int d   = dg * 4 + s;

    const bool active = (d < 26);
    if (active) {
        const float* xp = x + (size_t)(bc * 64 + d) * 4096;
#pragma unroll
        for (int it = 0; it < 8; ++it) {
            int idx = it * 64 + l;            // float4 index in 64x32 tile
            int row = idx >> 3, q = idx & 7;  // row<64, first 8 quads of W=64
            const float* g = xp + row * 64 + q * 4;
            __builtin_amdgcn_global_load_lds(
                (const __attribute__((address_space(1))) void*)g,
                (__attribute__((address_space(3))) void*)(&xs[s][it * 256]),
                16, 0, 0);
        }
    }

    if (dg != 7) {  // dg==7 blocks are pure zero-fill, never read sC
        // vectorized C stage: thread t covers C[8t..8t+7] -> row t>>3, col (t&7)*8
        {
            const float4* cg = (const float4*)(C + t * 8);
            float4 g0 = cg[0], g1 = cg[1];
            float* dst = sC + (t >> 3) * 68 + (t & 7) * 8;
            *(float4*)(dst)     = g0;
            *(float4*)(dst + 4) = g1;
        }
        __syncthreads();
    }

    float* op = out + (size_t)(bc * 32 + d) * 1024;

    if (!active) {
        const float4 z = make_float4(0.f, 0.f, 0.f, 0.f);
#pragma unroll
        for (int j = 0; j < 4; ++j)
            *(float4*)(op + (j * 64 + l) * 4) = z;
        return;
    }

    const float* xss = xs[s] + wq * 4;
    const float* cp  = sC + hb * 68;

    float4 a0 = make_float4(0.f, 0.f, 0.f, 0.f);
    float4 a1 = a0, a2 = a0, a3 = a0;

#pragma unroll 4
    for (int k4 = 0; k4 < 64; k4 += 4) {
        const float4 c0 = *(const float4*)(cp + k4);
        const float4 c1 = *(const float4*)(cp + 8 * 68 + k4);
        const float4 c2 = *(const float4*)(cp + 16 * 68 + k4);
        const float4 c3 = *(const float4*)(cp + 24 * 68 + k4);
        const float4 x0 = *(const float4*)(xss + (k4 + 0) * 32);
        const float4 x1 = *(const float4*)(xss + (k4 + 1) * 32);
        const float4 x2 = *(const float4*)(xss + (k4 + 2) * 32);
        const float4 x3 = *(const float4*)(xss + (k4 + 3) * 32);

        FMA4(a0, c0.x, x0); FMA4(a0, c0.y, x1); FMA4(a0, c0.z, x2); FMA4(a0, c0.w, x3);
        FMA4(a1, c1.x, x0); FMA4(a1, c1.y, x1); FMA4(a1, c1.z, x2); FMA4(a1, c1.w, x3);
        FMA4(a2, c2.x, x0); FMA4(a2, c2.y, x1); FMA4(a2, c2.z, x2); FMA4(a2, c2.w, x3);
        FMA4(a3, c3.x, x0); FMA4(a3, c3.y, x1); FMA4(a3, c3.z, x2); FMA4(a3, c3.w, x3);
    }

    // mask w >= 26 (wq==6: zero .z/.w for w=26,27; wq==7 fully zero)
    const int w0 = wq * 4;
    if (w0 >= 26) {
        a0 = a1 = a2 = a3 = make_float4(0.f, 0.f, 0.f, 0.f);
    } else if (w0 == 24) {
        a0.z = a0.w = 0.f; a1.z = a1.w = 0.f;
        a2.z = a2.w = 0.f; a3.z = a3.w = 0.f;
    }

    *(float4*)(op + hb * 32 + w0)        = a0;
    *(float4*)(op + (hb + 8) * 32 + w0)  = a1;
    *(float4*)(op + (hb + 16) * 32 + w0) = a2;
    *(float4*)(op + (hb + 24) * 32 + w0) = a3;
}

extern "C" void kernel_launch(void* const* d_in, const int* in_sizes, int n_in,
                              void* d_out, int out_size, void* d_ws, size_t ws_size,
                              hipStream_t stream) {
    const float* x = (const float*)d_in[0];
    float* out = (float*)d_out;
    float* C = (float*)d_ws;  // 32*64 fp32 = 8 KB scratch

    hipLaunchKernelGGL(build_C_kernel, dim3(1), dim3(1024), 0, stream, C);
    hipLaunchKernelGGL(spectral_pool_kernel, dim3(2048), dim3(256), 0, stream,
                       x, C, out);
}